// Round 11
// baseline (129.010 us; speedup 1.0000x reference)
//
#include <hip/hip_runtime.h>
#include <type_traits>

#define B_   32
#define T_   512
#define D_   512
#define F_   256
#define MEL  4096
#define EPS_ 1e-5f

typedef __attribute__((ext_vector_type(8))) short bf16x8;
typedef __attribute__((ext_vector_type(4))) float f32x4;

#define MEMPIN() asm volatile("" ::: "memory")

__device__ inline unsigned short f2bf(float f) {
    unsigned u = __float_as_uint(f);
    unsigned r = (u + 0x7fff + ((u >> 16) & 1)) >> 16;   // RNE
    return (unsigned short)r;
}

// ---------------------------------------------------------------------------
// prep: weight transpose/convert (blocks 0..2303) + per-batch cumsum & idx
// precompute (blocks 2304..2335). gidx[b][pos] = source row, or -1 (masked).
// ---------------------------------------------------------------------------
#define PREP_WBLOCKS 2304   // (3*D_*F_ + 3*F_*F_) / 256

__global__ __launch_bounds__(256)
void prep_kernel(const float* __restrict__ w1, const float* __restrict__ w2,
                 const int* __restrict__ tgt,
                 unsigned short* __restrict__ w1T, unsigned short* __restrict__ w2T,
                 int* __restrict__ gidx)
{
    __shared__ int lcum[T_];
    __shared__ int wsum[4];

    int bid = blockIdx.x;
    int tid = threadIdx.x;
    if (bid < PREP_WBLOCKS) {
        int idx = bid * 256 + tid;
        if (idx < 3 * D_ * F_) {
            int kk = idx / F_, f = idx % F_;
            w1T[(size_t)f * (3 * D_) + kk] = f2bf(w1[idx]);
        } else {
            int j = idx - 3 * D_ * F_;
            int kk = j / F_, f = j % F_;
            w2T[(size_t)f * (3 * F_) + kk] = f2bf(w2[j]);
        }
        return;
    }

    int b = bid - PREP_WBLOCKS;
    int t0 = tid * 2;
    int a0 = tgt[b * T_ + t0], a1 = tgt[b * T_ + t0 + 1];
    int lane = tid & 63, w = tid >> 6;
    int v = a0 + a1;
#pragma unroll
    for (int o = 1; o < 64; o <<= 1) { int u = __shfl_up(v, o); if (lane >= o) v += u; }
    if (lane == 63) wsum[w] = v;
    __syncthreads();
    int base = 0;
#pragma unroll
    for (int i = 0; i < 4; ++i) if (i < w) base += wsum[i];
    int incl = base + v;
    lcum[t0]     = incl - a1;
    lcum[t0 + 1] = incl;
    __syncthreads();

    int total = lcum[T_ - 1];
#pragma unroll
    for (int k = 0; k < MEL / 256; ++k) {
        int pos = tid + k * 256;
        int lo = 0, hi = T_;
        while (lo < hi) { int mid = (lo + hi) >> 1; if (lcum[mid] <= pos) lo = mid + 1; else hi = mid; }
        gidx[b * MEL + pos] = (pos < total) ? min(lo, T_ - 1) : -1;
    }
}

// ---------------------------------------------------------------------------
// Conv1d(K=3,SAME)+bias+LN+ReLU via bf16 MFMA — BARRIER-FREE K-loop.
// MT=64 rows, 512 thr = 8 waves (2 rowgroups x 4 fgroups), acc[2][4]/wave.
// A (im2col) in LDS, staged once (single barrier), read-only thereafter.
// B: per-wave register prefetch queue Bq[3] (3-step lead, 32-k per step) from
// L2-resident wT — no LDS staging, no barriers, no manual vmcnt; waits are
// compiler-computed from the pinned straight-line issue order.
// Gather rides per-wave: set q (2 rows) loads at step 2q, stores at step
// 2(q+3), slot q%3 — 6-step (~1000 cyc) lead covers L3.
// ---------------------------------------------------------------------------
template<int IN_D, typename InT, bool FUSE_DUR, int GP, int GBASE>
__global__ __launch_bounds__(512, 2)
void conv_mfma_kernel(const InT* __restrict__ x, const unsigned short* __restrict__ wT,
                      const float* __restrict__ bias, const float* __restrict__ gamma,
                      const float* __restrict__ beta, unsigned short* __restrict__ out,
                      const float* __restrict__ wl, const float* __restrict__ bl,
                      float* __restrict__ dur,
                      const float* __restrict__ xf, const int* __restrict__ gidx,
                      float* __restrict__ gout)
{
    constexpr int MT = 64;
    constexpr int KT = 3 * IN_D;
    constexpr int KSTEPS = KT / 32;                  // 48 (conv1) / 24 (conv2)
    static_assert(2 * GP <= KSTEPS, "gather sets must fit in even steps");

    __shared__ __align__(16) char xs_raw[(MT + 2) * IN_D * 2];
    __shared__ float red[MT][8];
    __shared__ float redD[MT][4];

    const int blocksPerBatch = T_ / MT;              // 8
    const int b  = blockIdx.x / blocksPerBatch;
    const int t0 = (blockIdx.x % blocksPerBatch) * MT;
    const int l  = threadIdx.x & 63;
    const int wv = threadIdx.x >> 6;                 // 0..7
    const int fg = wv & 3;
    const int rg = wv >> 2;

    // ---- stage A rows t0-1 .. t0+MT into LDS as bf16, swizzled ----
    constexpr int CH = (MT + 2) * IN_D / 8;
    for (int c = threadIdx.x; c < CH; c += 512) {
        int j  = c / (IN_D / 8);
        int d8 = (c % (IN_D / 8)) * 8;
        int t  = t0 - 1 + j;
        uint4 pk = make_uint4(0u, 0u, 0u, 0u);
        if (t >= 0 && t < T_) {
            if constexpr (std::is_same_v<InT, float>) {
                const float4* src = reinterpret_cast<const float4*>(&x[((size_t)b * T_ + t) * IN_D + d8]);
                float4 a0 = src[0], a1 = src[1];
                pk.x = (unsigned)f2bf(a0.x) | ((unsigned)f2bf(a0.y) << 16);
                pk.y = (unsigned)f2bf(a0.z) | ((unsigned)f2bf(a0.w) << 16);
                pk.z = (unsigned)f2bf(a1.x) | ((unsigned)f2bf(a1.y) << 16);
                pk.w = (unsigned)f2bf(a1.z) | ((unsigned)f2bf(a1.w) << 16);
            } else {
                pk = *reinterpret_cast<const uint4*>(&x[((size_t)b * T_ + t) * IN_D + d8]);
            }
        }
        int byte = ((j * IN_D + d8) * 2) ^ ((j & 7) << 4);
        *reinterpret_cast<uint4*>(&xs_raw[byte]) = pk;
    }

    float bv[4], gv[4], bev[4], wlv[4];
#pragma unroll
    for (int n = 0; n < 4; ++n) {
        int f = fg * 64 + n * 16 + (l & 15);
        bv[n] = bias[f]; gv[n] = gamma[f]; bev[n] = beta[f];
        if constexpr (FUSE_DUR) wlv[n] = wl[f];
    }
    float blv = 0.f;
    if constexpr (FUSE_DUR) blv = bl[0];

    __syncthreads();                                 // A tile ready; read-only after

    // ---- gather assignment: GROWS = 2*GP consecutive rows per wave ----
    constexpr int GROWS = 2 * GP;
    const int rbase = GBASE + (blockIdx.x * 8 + wv) * GROWS;
    int gidxv = gidx[rbase + min(l, GROWS - 1)];
    MEMPIN();

    // ---- per-wave B loads (registers, from L2-resident wT) ----
    const int f_lane = fg * 64 + (l & 15);
    const int k_lane = (l >> 4) * 8;
    auto loadB = [&](bf16x8* dst, int s) {
        if (s < KSTEPS) {
            const unsigned short* p = &wT[(size_t)f_lane * KT + s * 32 + k_lane];
#pragma unroll
            for (int n = 0; n < 4; ++n)
                dst[n] = *reinterpret_cast<const bf16x8*>(p + (size_t)n * 16 * KT);
        }
    };
    auto loadA = [&](bf16x8* dst, int kk) {
        int kp = kk / IN_D;                          // conv tap 0..2 (compile-time per step)
        int dbase = (kk % IN_D) + k_lane;
#pragma unroll
        for (int m = 0; m < 2; ++m) {
            int j = rg * 32 + m * 16 + (l & 15) + kp;
            int byte = ((j * IN_D + dbase) * 2) ^ ((j & 7) << 4);
            dst[m] = *reinterpret_cast<const bf16x8*>(&xs_raw[byte]);
        }
    };

    // gather set load/store: 2 rows/set, 2 dwordx4 per lane per row.
    // ALWAYS load (clamped idx; zeroed at store) — keeps issue order uniform.
    float4 ga[3][2][2];
    auto loadSet = [&](int slot, int s) {
#pragma unroll
        for (int i = 0; i < 2; ++i) {
            int li = 2 * s + i;
            int ix = __shfl(gidxv, li);
            int r  = rbase + li;
            const float* src = xf + ((size_t)(r >> 12) * T_ + max(ix, 0)) * D_ + l * 4;
            ga[slot][i][0] = *reinterpret_cast<const float4*>(src);
            ga[slot][i][1] = *reinterpret_cast<const float4*>(src + 256);
        }
    };
    auto storeSet = [&](int slot, int s) {
#pragma unroll
        for (int i = 0; i < 2; ++i) {
            int li = 2 * s + i;
            int ix = __shfl(gidxv, li);
            int r  = rbase + li;
            float4 a = ga[slot][i][0], c = ga[slot][i][1];
            if (ix < 0) { a = make_float4(0.f,0.f,0.f,0.f); c = make_float4(0.f,0.f,0.f,0.f); }
            float* d = gout + (size_t)r * D_ + l * 4;
            *reinterpret_cast<float4*>(d)       = a;
            *reinterpret_cast<float4*>(d + 256) = c;
        }
    };

    f32x4 acc[2][4];
#pragma unroll
    for (int m = 0; m < 2; ++m)
#pragma unroll
        for (int n = 0; n < 4; ++n) acc[m][n] = (f32x4){0.f, 0.f, 0.f, 0.f};

    // ---- prologue: B queue depth 3 ----
    bf16x8 Bq[3][4];
    loadB(Bq[0], 0); MEMPIN();
    loadB(Bq[1], 1); MEMPIN();
    loadB(Bq[2], 2); MEMPIN();

    // ---- barrier-free step loop (fully unrolled; all queue indices static) ----
#pragma unroll
    for (int s = 0; s < KSTEPS; ++s) {
        bf16x8 Av[2];
        loadA(Av, s * 32);
        {
            bf16x8* Bv = Bq[s % 3];
#pragma unroll
            for (int m = 0; m < 2; ++m)
#pragma unroll
                for (int n = 0; n < 4; ++n)
                    acc[m][n] = __builtin_amdgcn_mfma_f32_16x16x32_bf16(Av[m], Bv[n], acc[m][n], 0, 0, 0);
        }
        MEMPIN();
        loadB(Bq[s % 3], s + 3);                     // refill freed slot
        MEMPIN();
        if ((s & 1) == 0) {
            int q = s >> 1;
            if (q >= 3 && q - 3 < GP) { storeSet((q - 3) % 3, q - 3); MEMPIN(); }
            if (q < GP)               { loadSet(q % 3, q);            MEMPIN(); }
        }
    }
    // tail: sets loaded but whose store step falls past the loop
#pragma unroll
    for (int j = (KSTEPS / 2 >= 3 ? KSTEPS / 2 - 3 : 0); j < GP; ++j)
        storeSet(j % 3, j);

    // ---- epilogue: bias, LN stats, LN+ReLU store, optional fused dur ----
#pragma unroll
    for (int m = 0; m < 2; ++m)
#pragma unroll
        for (int q = 0; q < 4; ++q) {
            float s = 0.f, s2 = 0.f;
#pragma unroll
            for (int n = 0; n < 4; ++n) {
                float v2 = acc[m][n][q] + bv[n];
                acc[m][n][q] = v2;
                s += v2; s2 += v2 * v2;
            }
#pragma unroll
            for (int o = 1; o < 16; o <<= 1) { s += __shfl_xor(s, o); s2 += __shfl_xor(s2, o); }
            int row = rg * 32 + m * 16 + (l >> 4) * 4 + q;   // C/D: col=l&15, row=(l>>4)*4+q
            if ((l & 15) == 0) { red[row][fg * 2] = s; red[row][fg * 2 + 1] = s2; }
        }
    __syncthreads();

#pragma unroll
    for (int m = 0; m < 2; ++m)
#pragma unroll
        for (int q = 0; q < 4; ++q) {
            int row = rg * 32 + m * 16 + (l >> 4) * 4 + q;
            float s  = red[row][0] + red[row][2] + red[row][4] + red[row][6];
            float s2 = red[row][1] + red[row][3] + red[row][5] + red[row][7];
            float mu  = s * (1.f / F_);
            float var = s2 * (1.f / F_) - mu * mu;
            float rs  = rsqrtf(var + EPS_);
            size_t rb2 = ((size_t)(b * T_ + t0 + row)) * F_;
            float part = 0.f;
#pragma unroll
            for (int n = 0; n < 4; ++n) {
                float y = (acc[m][n][q] - mu) * rs * gv[n] + bev[n];
                y = fmaxf(y, 0.f);
                out[rb2 + fg * 64 + n * 16 + (l & 15)] = f2bf(y);
                if constexpr (FUSE_DUR) part = fmaf(y, wlv[n], part);
            }
            if constexpr (FUSE_DUR) {
#pragma unroll
                for (int o = 1; o < 16; o <<= 1) part += __shfl_xor(part, o);
                if ((l & 15) == 0) redD[row][fg] = part;
            }
        }

    if constexpr (FUSE_DUR) {
        __syncthreads();
        if (threadIdx.x < MT) {
            float s = redD[threadIdx.x][0] + redD[threadIdx.x][1]
                    + redD[threadIdx.x][2] + redD[threadIdx.x][3] + blv;
            dur[(size_t)b * T_ + t0 + threadIdx.x] = fmaxf(s, 0.f);
        }
    }
}

extern "C" void kernel_launch(void* const* d_in, const int* in_sizes, int n_in,
                              void* d_out, int out_size, void* d_ws, size_t ws_size,
                              hipStream_t stream)
{
    const float* x      = (const float*)d_in[0];
    const int*   target = (const int*)d_in[1];
    const float* w1  = (const float*)d_in[3];
    const float* b1  = (const float*)d_in[4];
    const float* g1  = (const float*)d_in[5];
    const float* be1 = (const float*)d_in[6];
    const float* w2  = (const float*)d_in[7];
    const float* b2  = (const float*)d_in[8];
    const float* g2  = (const float*)d_in[9];
    const float* be2 = (const float*)d_in[10];
    const float* wl  = (const float*)d_in[11];
    const float* bl  = (const float*)d_in[12];

    float* out = (float*)d_out;                        // (B, MEL, D)
    float* dur = out + (size_t)B_ * MEL * D_;          // (B, T)

    char* ws = (char*)d_ws;
    unsigned short* w1T = (unsigned short*)ws;         ws += (size_t)F_ * (3 * D_) * 2;
    unsigned short* w2T = (unsigned short*)ws;         ws += (size_t)F_ * (3 * F_) * 2;
    unsigned short* h1  = (unsigned short*)ws;         ws += (size_t)B_ * T_ * F_ * 2;
    unsigned short* h2  = (unsigned short*)ws;         ws += (size_t)B_ * T_ * F_ * 2;
    int*            gidx = (int*)ws;                   // B_*MEL ints

    prep_kernel<<<PREP_WBLOCKS + B_, 256, 0, stream>>>(w1, w2, target, w1T, w2T, gidx);

    // conv1 carries gather rows 0..98303 (24 sets x 2 rows x 8 waves x 256 blocks),
    // conv2 carries rows 98304..131071 (8 sets within 12 even steps).
    conv_mfma_kernel<D_, float, false, 24, 0><<<B_ * (T_ / 64), 512, 0, stream>>>(
        x, w1T, b1, g1, be1, h1, nullptr, nullptr, nullptr, x, gidx, out);
    conv_mfma_kernel<F_, unsigned short, true, 8, 98304><<<B_ * (T_ / 64), 512, 0, stream>>>(
        h1, w2T, b2, g2, be2, h2, wl, bl, dur, x, gidx, out);
}